// Round 7
// baseline (101.567 us; speedup 1.0000x reference)
//
#include <hip/hip_runtime.h>

#define BATCH   8
#define SHAPE_N 8192
#define SKEL_M  2048
#define CHUNK   1024   // b-points per LDS chunk: 1024 * 32 B = 32 KB

// MFMA frag types (gfx950: 32x32x16 bf16 — A/B = 8 bf16 (4 VGPRs), C/D = 16 f32)
typedef short bf16x8 __attribute__((ext_vector_type(8)));
typedef float f32x16 __attribute__((ext_vector_type(16)));
union FragU { bf16x8 v; uint4 u4; };

// round-to-nearest-even f32 -> bf16 (result in low 16 bits)
__device__ __forceinline__ unsigned int f2bf(float a) {
    unsigned int u = __float_as_uint(a);
    return (u + 0x7FFFu + ((u >> 16) & 1u)) >> 16;
}
__device__ __forceinline__ float bf2f(unsigned int h) {
    return __uint_as_float(h << 16);
}
__device__ __forceinline__ unsigned int pack2(unsigned int lo, unsigned int hi) {
    return lo | (hi << 16);
}
// v ~= hi + lo (two bf16), residual ~2^-16 relative
__device__ __forceinline__ void bfsplit(float v, unsigned int& h, unsigned int& l) {
    h = f2bf(v);
    l = f2bf(v - bf2f(h));
}

// ---------------------------------------------------------------------------
// One direction, one wave owns 32 a-points (full B scan => final min).
// D[m][n] = sum_k A[m,k] B[k,n] = rb_m - 2 b_m.a_n with hi/lo bf16 split:
//   k=0..2  c_hi x a_hi   k=3 rb_hi x 1
//   k=4..6  c_hi x a_lo   k=7 rb_lo x 1
//   k=8..10 c_lo x a_hi   k=11..15 zero          (c = -2b; ra added in fp32)
// A-frag lanes<32 hold k=0..7 of row m=lane&31; lanes>=32 hold k=8..15.
// LDS per 32-point group: 32x uint4 lo-half then 32x uint4 hi-half; the
// wave's ds_read_b128 at off = g*1024 + (l>>5)*512 + (l&31)*16 is the
// standard consecutive-b128 conflict-free pattern.
// ---------------------------------------------------------------------------
template <int SA, int SB, int NB>
__device__ __forceinline__ float cd_dir_mfma(
    const float* __restrict__ Araw,   // batch base, a-side (stride SA)
    const float* __restrict__ Braw,   // batch base, b-side (stride SB)
    int a0, uint4* sB, float* p_ra)
{
    const int tid = threadIdx.x;
    const int l = tid & 63;

    // resident B-operand frag: col n = l&31 (lane and lane^32 share a-point)
    const float* p = Araw + (size_t)(a0 + (l & 31)) * SA;
    const float x = p[0], y = p[1], z = p[2];
    *p_ra = x * x + y * y + z * z;
    unsigned int hx, lx, hy, ly, hz, lz;
    bfsplit(x, hx, lx); bfsplit(y, hy, ly); bfsplit(z, hz, lz);
    const unsigned int one = 0x3F80u;
    FragU bf;
    if (l < 32) {   // k=0..7: (a_hi, 1, a_lo, 1)
        bf.u4 = make_uint4(pack2(hx, hy), pack2(hz, one),
                           pack2(lx, ly), pack2(lz, one));
    } else {        // k=8..15: (a_hi, 0, 0, 0)
        bf.u4 = make_uint4(pack2(hx, hy), pack2(hz, 0u), 0u, 0u);
    }

    const f32x16 Z = {0,0,0,0,0,0,0,0,0,0,0,0,0,0,0,0};
    float rmin = 3.4e38f;
    const unsigned int off0 =
        (unsigned int)((l >> 5) * 512 + (l & 31) * 16);

    for (int c = 0; c < NB; c += CHUNK) {
        __syncthreads();                       // previous chunk fully consumed
        const float* src = Braw + (size_t)c * SB;
        for (int i = tid; i < CHUNK; i += 256) {
            const float* q = src + (size_t)i * SB;
            const float bx = q[0], by = q[1], bz = q[2];
            const float cx = -2.f * bx, cy = -2.f * by, cz = -2.f * bz;
            const float rb = bx * bx + by * by + bz * bz;
            unsigned int chx, clx, chy, cly, chz, clz, rbh, rbl;
            bfsplit(cx, chx, clx); bfsplit(cy, chy, cly); bfsplit(cz, chz, clz);
            bfsplit(rb, rbh, rbl);
            const int g = i >> 5, r = i & 31;
            sB[g * 64 + r]      = make_uint4(pack2(chx, chy), pack2(chz, rbh),
                                             pack2(chx, chy), pack2(chz, rbl));
            sB[g * 64 + 32 + r] = make_uint4(pack2(clx, cly), pack2(clz, 0u),
                                             0u, 0u);
        }
        __syncthreads();

        unsigned int o = off0;
#pragma unroll 4
        for (int g = 0; g < CHUNK / 32; ++g) {
            FragU af;
            af.u4 = *(const uint4*)((const char*)sB + o);
            o += 1024;
            f32x16 D = __builtin_amdgcn_mfma_f32_32x32x16_bf16(af.v, bf.v, Z, 0, 0, 0);
            const float m0 = fminf(fminf(D[0], D[1]),   fminf(D[2], D[3]));
            const float m1 = fminf(fminf(D[4], D[5]),   fminf(D[6], D[7]));
            const float m2 = fminf(fminf(D[8], D[9]),   fminf(D[10], D[11]));
            const float m3 = fminf(fminf(D[12], D[13]), fminf(D[14], D[15]));
            rmin = fminf(rmin, fminf(fminf(m0, m1), fminf(m2, m3)));
        }
    }
    // lane l and l^32 cover complementary rows of the same col (a-point)
    rmin = fminf(rmin, __shfl_xor(rmin, 32, 64));
    return rmin;
}

// ---------------------------------------------------------------------------
// blocks [0,128):   dir2 (a = skel, b = shape, 8 chunks) — heavier, first.
// blocks [128,640): dir1 (a = shape, b = skel, 2 chunks).
// Epilogue: d = sqrt(max(ra+rmin,0)) on lanes<32, block reduce, one atomicAdd.
// ---------------------------------------------------------------------------
__global__ __launch_bounds__(256) void cd_mfma_kernel(
    const float* __restrict__ shape, const float* __restrict__ skel,
    float* __restrict__ out)
{
    __shared__ uint4 sB[CHUNK * 2];    // 32 KB
    __shared__ float s_wsum[4];
    const int tid = threadIdx.x;
    const int l = tid & 63, wv = tid >> 6;
    const int bid = blockIdx.x;

    float ra, rmin;
    if (bid < 128) {                 // dir2: a = skel (stride 3), b = shape (stride 6)
        const int b = bid >> 4, s16 = bid & 15;
        rmin = cd_dir_mfma<3, 6, SHAPE_N>(skel + (size_t)b * SKEL_M * 3,
                                          shape + (size_t)b * SHAPE_N * 6,
                                          s16 * 128 + wv * 32, sB, &ra);
    } else {                         // dir1: a = shape (stride 6), b = skel (stride 3)
        const int j = bid - 128;
        const int b = j >> 6, sub = j & 63;
        rmin = cd_dir_mfma<6, 3, SKEL_M>(shape + (size_t)b * SHAPE_N * 6,
                                         skel + (size_t)b * SKEL_M * 3,
                                         sub * 128 + wv * 32, sB, &ra);
    }

    float d = (l < 32) ? sqrtf(fmaxf(ra + rmin, 0.f)) : 0.f;
    for (int o = 32; o; o >>= 1) d += __shfl_down(d, o, 64);
    if (l == 0) s_wsum[wv] = d;
    __syncthreads();
    if (tid == 0)
        atomicAdd(out, (s_wsum[0] + s_wsum[1] + s_wsum[2] + s_wsum[3]) * 1e-4f);
}

extern "C" void kernel_launch(void* const* d_in, const int* in_sizes, int n_in,
                              void* d_out, int out_size, void* d_ws, size_t ws_size,
                              hipStream_t stream) {
    const float* shape = (const float*)d_in[0];   // (8, 8192, 6) — use first 3
    const float* skel  = (const float*)d_in[1];   // (8, 2048, 3)
    float* out         = (float*)d_out;           // scalar

    hipMemsetAsync(out, 0, sizeof(float), stream);
    cd_mfma_kernel<<<640, 256, 0, stream>>>(shape, skel, out);
}

// Round 8
// 80.207 us; speedup vs baseline: 1.2663x; 1.2663x over previous
//
#include <hip/hip_runtime.h>

#define BATCH   8
#define SHAPE_N 8192
#define SKEL_M  2048
#define CHUNK   1024   // b-points per LDS chunk: 1024 * 32 B = 32 KB

// MFMA frag types (gfx950: 32x32x16 bf16 — A/B = 8 bf16 (4 VGPRs), C/D = 16 f32)
typedef short bf16x8 __attribute__((ext_vector_type(8)));
typedef float f32x16 __attribute__((ext_vector_type(16)));
union FragU { bf16x8 v; uint4 u4; };

// round-to-nearest-even f32 -> bf16 (result in low 16 bits)
__device__ __forceinline__ unsigned int f2bf(float a) {
    unsigned int u = __float_as_uint(a);
    return (u + 0x7FFFu + ((u >> 16) & 1u)) >> 16;
}
__device__ __forceinline__ float bf2f(unsigned int h) {
    return __uint_as_float(h << 16);
}
__device__ __forceinline__ unsigned int pack2(unsigned int lo, unsigned int hi) {
    return lo | (hi << 16);
}
// v ~= hi + lo (two bf16), residual ~2^-16 relative
__device__ __forceinline__ void bfsplit(float v, unsigned int& h, unsigned int& l) {
    h = f2bf(v);
    l = f2bf(v - bf2f(h));
}

// ---------------------------------------------------------------------------
// Scan 2048 b-points against this wave's 32 resident a-points.
// D[m][n] = rb_m - 2 b_m.a_n via hi/lo bf16 split across K=16 (exact to the
// checker — layout identical to the passing R7 kernel):
//   k=0..2  c_hi x a_hi   k=3 rb_hi x 1
//   k=4..6  c_hi x a_lo   k=7 rb_lo x 1
//   k=8..10 c_lo x a_hi   k=11..15 zero          (c = -2b; ra added in fp32)
// Latency structure: C=0 => all MFMAs independent; componentwise running min
// (16 parallel 1-fmin chains) instead of a per-step reduction tree.
// ---------------------------------------------------------------------------
template <int SA, int SB>
__device__ __forceinline__ float cd_scan(
    const float* __restrict__ Araw,   // a-side: first of this wave's points
    const float* __restrict__ Braw,   // b-side: 2048-point scan base
    uint4* sB, float* p_ra)
{
    const int tid = threadIdx.x;
    const int l = tid & 63;

    // resident B-operand frag: col n = l&31 (lane and lane^32 share a-point)
    const float* p = Araw + (size_t)(l & 31) * SA;
    const float x = p[0], y = p[1], z = p[2];
    *p_ra = x * x + y * y + z * z;
    unsigned int hx, lx, hy, ly, hz, lz;
    bfsplit(x, hx, lx); bfsplit(y, hy, ly); bfsplit(z, hz, lz);
    const unsigned int one = 0x3F80u;
    FragU bf;
    if (l < 32) {   // k=0..7: (a_hi, 1, a_lo, 1)
        bf.u4 = make_uint4(pack2(hx, hy), pack2(hz, one),
                           pack2(lx, ly), pack2(lz, one));
    } else {        // k=8..15: (a_hi, 0, 0, 0)
        bf.u4 = make_uint4(pack2(hx, hy), pack2(hz, 0u), 0u, 0u);
    }

    const f32x16 Z = {0,0,0,0,0,0,0,0,0,0,0,0,0,0,0,0};
    f32x16 Dmin;
#pragma unroll
    for (int j = 0; j < 16; ++j) Dmin[j] = 3.4e38f;
    const unsigned int off0 = (unsigned int)((l >> 5) * 512 + (l & 31) * 16);

    for (int c = 0; c < 2048; c += CHUNK) {
        __syncthreads();                       // previous chunk fully consumed
        const float* src = Braw + (size_t)c * SB;
        for (int i = tid; i < CHUNK; i += 256) {
            const float* q = src + (size_t)i * SB;
            const float bx = q[0], by = q[1], bz = q[2];
            const float cx = -2.f * bx, cy = -2.f * by, cz = -2.f * bz;
            const float rb = bx * bx + by * by + bz * bz;
            unsigned int chx, clx, chy, cly, chz, clz, rbh, rbl;
            bfsplit(cx, chx, clx); bfsplit(cy, chy, cly); bfsplit(cz, chz, clz);
            bfsplit(rb, rbh, rbl);
            const int g = i >> 5, r = i & 31;
            sB[g * 64 + r]      = make_uint4(pack2(chx, chy), pack2(chz, rbh),
                                             pack2(chx, chy), pack2(chz, rbl));
            sB[g * 64 + 32 + r] = make_uint4(pack2(clx, cly), pack2(clz, 0u),
                                             0u, 0u);
        }
        __syncthreads();

        unsigned int o = off0;
#pragma unroll 8
        for (int g = 0; g < CHUNK / 32; ++g) {
            FragU af;
            af.u4 = *(const uint4*)((const char*)sB + o);
            o += 1024;
            f32x16 D = __builtin_amdgcn_mfma_f32_32x32x16_bf16(af.v, bf.v, Z, 0, 0, 0);
#pragma unroll
            for (int j = 0; j < 16; ++j) Dmin[j] = fminf(Dmin[j], D[j]);
        }
    }
    const float m0 = fminf(fminf(Dmin[0],  Dmin[1]),  fminf(Dmin[2],  Dmin[3]));
    const float m1 = fminf(fminf(Dmin[4],  Dmin[5]),  fminf(Dmin[6],  Dmin[7]));
    const float m2 = fminf(fminf(Dmin[8],  Dmin[9]),  fminf(Dmin[10], Dmin[11]));
    const float m3 = fminf(fminf(Dmin[12], Dmin[13]), fminf(Dmin[14], Dmin[15]));
    float rmin = fminf(fminf(m0, m1), fminf(m2, m3));
    // lane l and l^32 cover complementary rows of the same col (a-point)
    rmin = fminf(rmin, __shfl_xor(rmin, 32, 64));
    return rmin;
}

// ---------------------------------------------------------------------------
// 1024 equal blocks (64 MFMA steps each), 4 blocks/CU, 16 waves/CU:
//   [0,512):    dir1 — a = shape (128 pts/block), b = full skel (2048).
//               Complete min => local sqrt+sum epilogue, atomicAdd to out.
//   [512,1024): dir2 — a = skel (128 pts/block), b = one of 4 shape quarters
//               (2048). Partial min => atomicMin(uint bits) into ws.
// ---------------------------------------------------------------------------
__global__ __launch_bounds__(256) void cd_main(
    const float* __restrict__ shape, const float* __restrict__ skel,
    unsigned int* __restrict__ ws, float* __restrict__ out)
{
    __shared__ uint4 sB[CHUNK * 2];    // 32 KB
    __shared__ float s_wsum[4];
    const int tid = threadIdx.x;
    const int l = tid & 63, wv = tid >> 6;
    const int bid = blockIdx.x;

    if (bid < 512) {                   // dir1: a = shape (stride 6), b = skel (stride 3)
        const int b = bid >> 6, sub = bid & 63;
        float ra;
        const float rmin = cd_scan<6, 3>(
            shape + ((size_t)b * SHAPE_N + sub * 128 + wv * 32) * 6,
            skel + (size_t)b * SKEL_M * 3, sB, &ra);
        float d = (l < 32) ? sqrtf(fmaxf(ra + rmin, 0.f)) : 0.f;
        for (int o = 32; o; o >>= 1) d += __shfl_down(d, o, 64);
        if (l == 0) s_wsum[wv] = d;
        __syncthreads();
        if (tid == 0)
            atomicAdd(out, (s_wsum[0] + s_wsum[1] + s_wsum[2] + s_wsum[3]) * 1e-4f);
    } else {                           // dir2: a = skel (stride 3), b = shape quarter (stride 6)
        const int j = bid - 512;
        const int b = j >> 6, rem = j & 63;
        const int asub = rem >> 2, bs = rem & 3;
        float ra;
        const float rmin = cd_scan<3, 6>(
            skel + ((size_t)b * SKEL_M + asub * 128 + wv * 32) * 3,
            shape + ((size_t)b * SHAPE_N + bs * 2048) * 6, sB, &ra);
        if (l < 32) {
            const float v = fmaxf(ra + rmin, 0.f);
            atomicMin(&ws[b * SKEL_M + asub * 128 + wv * 32 + l],
                      __float_as_uint(v));
        }
    }
}

// ---------------------------------------------------------------------------
// Finalize dir2: 16384 mins -> sqrt -> sum. 16 blocks x 256 thr, uint4 loads.
// ---------------------------------------------------------------------------
__global__ __launch_bounds__(256) void cd_finalize(
    const uint4* __restrict__ ws, float* __restrict__ out)
{
    __shared__ float s_wsum[4];
    const uint4 v = ws[blockIdx.x * 256 + threadIdx.x];
    float s = sqrtf(__uint_as_float(v.x)) + sqrtf(__uint_as_float(v.y)) +
              sqrtf(__uint_as_float(v.z)) + sqrtf(__uint_as_float(v.w));
    for (int o = 32; o; o >>= 1) s += __shfl_down(s, o, 64);
    const int lane = threadIdx.x & 63, wave = threadIdx.x >> 6;
    if (lane == 0) s_wsum[wave] = s;
    __syncthreads();
    if (threadIdx.x == 0)
        atomicAdd(out, (s_wsum[0] + s_wsum[1] + s_wsum[2] + s_wsum[3]) * 1e-4f);
}

extern "C" void kernel_launch(void* const* d_in, const int* in_sizes, int n_in,
                              void* d_out, int out_size, void* d_ws, size_t ws_size,
                              hipStream_t stream) {
    const float* shape = (const float*)d_in[0];   // (8, 8192, 6) — use first 3
    const float* skel  = (const float*)d_in[1];   // (8, 2048, 3)
    float* out         = (float*)d_out;           // scalar
    unsigned int* ws   = (unsigned int*)d_ws;     // 16384 uints = 64 KB

    hipMemsetAsync(out, 0, sizeof(float), stream);
    hipMemsetAsync(ws, 0xFF, (size_t)BATCH * SKEL_M * sizeof(unsigned int), stream);
    cd_main<<<1024, 256, 0, stream>>>(shape, skel, ws, out);
    cd_finalize<<<BATCH * SKEL_M / 1024, 256, 0, stream>>>((const uint4*)ws, out);
}

// Round 9
// 74.961 us; speedup vs baseline: 1.3549x; 1.0700x over previous
//
#include <hip/hip_runtime.h>

#define BATCH   8
#define SHAPE_N 8192
#define SKEL_M  2048
#define CHUNK   1024   // b-points per LDS chunk: 1024 * 32 B = 32 KB

// ws layout (floats):
//   [0, 512):        dir1 per-block partial sums (plain stores)
//   [512, 512+65536): dir2 partial mins, [quarter q<4][batch b<8][apt 2048]
// Every slot read by cd_reduce is written by cd_main in the same iteration,
// so no ws init and no atomics are needed (re-poison-safe).
#define WS2_OFF 512

// MFMA frag types (gfx950: 32x32x16 bf16 — A/B = 8 bf16 (4 VGPRs), C/D = 16 f32)
typedef short bf16x8 __attribute__((ext_vector_type(8)));
typedef float f32x16 __attribute__((ext_vector_type(16)));
union FragU { bf16x8 v; uint4 u4; };

// round-to-nearest-even f32 -> bf16 (result in low 16 bits)
__device__ __forceinline__ unsigned int f2bf(float a) {
    unsigned int u = __float_as_uint(a);
    return (u + 0x7FFFu + ((u >> 16) & 1u)) >> 16;
}
__device__ __forceinline__ float bf2f(unsigned int h) {
    return __uint_as_float(h << 16);
}
__device__ __forceinline__ unsigned int pack2(unsigned int lo, unsigned int hi) {
    return lo | (hi << 16);
}
// v ~= hi + lo (two bf16), residual ~2^-16 relative
__device__ __forceinline__ void bfsplit(float v, unsigned int& h, unsigned int& l) {
    h = f2bf(v);
    l = f2bf(v - bf2f(h));
}

// ---------------------------------------------------------------------------
// Scan 2048 b-points against this wave's 32 resident a-points.
// D[m][n] = rb_m - 2 b_m.a_n via hi/lo bf16 split across K=16 (bit-identical
// to the passing R7/R8 kernels):
//   k=0..2  c_hi x a_hi   k=3 rb_hi x 1
//   k=4..6  c_hi x a_lo   k=7 rb_lo x 1
//   k=8..10 c_lo x a_hi   k=11..15 zero          (c = -2b; ra added in fp32)
// Per-step min: 8x v_min3_f32 tree (nested fminf triples) -> 1 min3 into the
// serial rmin chain; MFMAs all independent (C=0).
// ---------------------------------------------------------------------------
template <int SA, int SB>
__device__ __forceinline__ float cd_scan(
    const float* __restrict__ Araw,   // a-side: first of this wave's 32 points
    const float* __restrict__ Braw,   // b-side: 2048-point scan base
    uint4* sB, float* p_ra)
{
    const int tid = threadIdx.x;
    const int l = tid & 63;

    // resident B-operand frag: col n = l&31 (lane and lane^32 share a-point)
    const float* p = Araw + (size_t)(l & 31) * SA;
    const float x = p[0], y = p[1], z = p[2];
    *p_ra = x * x + y * y + z * z;
    unsigned int hx, lx, hy, ly, hz, lz;
    bfsplit(x, hx, lx); bfsplit(y, hy, ly); bfsplit(z, hz, lz);
    const unsigned int one = 0x3F80u;
    FragU bf;
    if (l < 32) {   // k=0..7: (a_hi, 1, a_lo, 1)
        bf.u4 = make_uint4(pack2(hx, hy), pack2(hz, one),
                           pack2(lx, ly), pack2(lz, one));
    } else {        // k=8..15: (a_hi, 0, 0, 0)
        bf.u4 = make_uint4(pack2(hx, hy), pack2(hz, 0u), 0u, 0u);
    }

    const f32x16 Z = {0,0,0,0,0,0,0,0,0,0,0,0,0,0,0,0};
    float rmin = 3.4e38f;
    const unsigned int off0 = (unsigned int)((l >> 5) * 512 + (l & 31) * 16);

    for (int c = 0; c < 2048; c += CHUNK) {
        __syncthreads();                       // previous chunk fully consumed
        const float* src = Braw + (size_t)c * SB;
        for (int i = tid; i < CHUNK; i += 256) {
            const float* q = src + (size_t)i * SB;
            const float bx = q[0], by = q[1], bz = q[2];
            const float cx = -2.f * bx, cy = -2.f * by, cz = -2.f * bz;
            const float rb = bx * bx + by * by + bz * bz;
            unsigned int chx, clx, chy, cly, chz, clz, rbh, rbl;
            bfsplit(cx, chx, clx); bfsplit(cy, chy, cly); bfsplit(cz, chz, clz);
            bfsplit(rb, rbh, rbl);
            const int g = i >> 5, r = i & 31;
            sB[g * 64 + r]      = make_uint4(pack2(chx, chy), pack2(chz, rbh),
                                             pack2(chx, chy), pack2(chz, rbl));
            sB[g * 64 + 32 + r] = make_uint4(pack2(clx, cly), pack2(clz, 0u),
                                             0u, 0u);
        }
        __syncthreads();

        unsigned int o = off0;
#pragma unroll 8
        for (int g = 0; g < CHUNK / 32; ++g) {
            FragU af;
            af.u4 = *(const uint4*)((const char*)sB + o);
            o += 1024;
            f32x16 D = __builtin_amdgcn_mfma_f32_32x32x16_bf16(af.v, bf.v, Z, 0, 0, 0);
            // 8x v_min3 tree + 1 min3 into rmin
            const float t0 = fminf(fminf(D[0],  D[1]),  D[2]);
            const float t1 = fminf(fminf(D[3],  D[4]),  D[5]);
            const float t2 = fminf(fminf(D[6],  D[7]),  D[8]);
            const float t3 = fminf(fminf(D[9],  D[10]), D[11]);
            const float t4 = fminf(fminf(D[12], D[13]), D[14]);
            const float u0 = fminf(fminf(t0, t1), t2);
            const float u1 = fminf(fminf(t3, t4), D[15]);
            rmin = fminf(rmin, fminf(u0, u1));
        }
    }
    // lane l and l^32 cover complementary rows of the same col (a-point)
    rmin = fminf(rmin, __shfl_xor(rmin, 32, 64));
    return rmin;
}

// ---------------------------------------------------------------------------
// 1024 equal blocks (64 MFMA steps each), 4 blocks/CU, 16 waves/CU:
//   [0,512):    dir1 — a = shape (128 pts), b = full skel. Complete min =>
//               sqrt+block-sum => plain store of one partial to ws[bid].
//   [512,1024): dir2 — a = skel (128 pts), b = one shape quarter. Partial
//               min => plain stores into this quarter's ws slice.
// ---------------------------------------------------------------------------
__global__ __launch_bounds__(256) void cd_main(
    const float* __restrict__ shape, const float* __restrict__ skel,
    float* __restrict__ ws)
{
    __shared__ uint4 sB[CHUNK * 2];    // 32 KB
    __shared__ float s_wsum[4];
    const int tid = threadIdx.x;
    const int l = tid & 63, wv = tid >> 6;
    const int bid = blockIdx.x;

    if (bid < 512) {                   // dir1: a = shape (stride 6), b = skel (stride 3)
        const int b = bid >> 6, sub = bid & 63;
        float ra;
        const float rmin = cd_scan<6, 3>(
            shape + ((size_t)b * SHAPE_N + sub * 128 + wv * 32) * 6,
            skel + (size_t)b * SKEL_M * 3, sB, &ra);
        float d = (l < 32) ? sqrtf(fmaxf(ra + rmin, 0.f)) : 0.f;
        for (int o = 32; o; o >>= 1) d += __shfl_down(d, o, 64);
        if (l == 0) s_wsum[wv] = d;
        __syncthreads();
        if (tid == 0)
            ws[bid] = s_wsum[0] + s_wsum[1] + s_wsum[2] + s_wsum[3];
    } else {                           // dir2: a = skel (stride 3), b = shape quarter (stride 6)
        const int j = bid - 512;
        const int b = j >> 6, rem = j & 63;
        const int asub = rem >> 2, bs = rem & 3;
        float ra;
        const float rmin = cd_scan<3, 6>(
            skel + ((size_t)b * SKEL_M + asub * 128 + wv * 32) * 3,
            shape + ((size_t)b * SHAPE_N + bs * 2048) * 6, sB, &ra);
        if (l < 32)
            ws[WS2_OFF + bs * (BATCH * SKEL_M) + b * SKEL_M +
               asub * 128 + wv * 32 + l] = ra + rmin;
    }
}

// ---------------------------------------------------------------------------
// Single-block reduce (no atomics, no pre-zeroed out): min-fold the 4 dir2
// quarters (float4 loads over 256 KB, L2-resident), clamp+sqrt+sum, add the
// 512 dir1 partials, write out[0].
// ---------------------------------------------------------------------------
__global__ __launch_bounds__(1024) void cd_reduce(
    const float* __restrict__ ws, float* __restrict__ out)
{
    __shared__ float s_wsum[16];
    const int t = threadIdx.x;
    float s = 0.f;

    const float4* w4 = (const float4*)(ws + WS2_OFF);
#pragma unroll
    for (int r = 0; r < 4; ++r) {
        const int i4 = r * 1024 + t;          // float4 index within 4096
        float4 v0 = w4[i4];
        const float4 v1 = w4[4096 + i4];
        const float4 v2 = w4[8192 + i4];
        const float4 v3 = w4[12288 + i4];
        v0.x = fminf(fminf(v0.x, v1.x), fminf(v2.x, v3.x));
        v0.y = fminf(fminf(v0.y, v1.y), fminf(v2.y, v3.y));
        v0.z = fminf(fminf(v0.z, v1.z), fminf(v2.z, v3.z));
        v0.w = fminf(fminf(v0.w, v1.w), fminf(v2.w, v3.w));
        s += sqrtf(fmaxf(v0.x, 0.f)) + sqrtf(fmaxf(v0.y, 0.f)) +
             sqrtf(fmaxf(v0.z, 0.f)) + sqrtf(fmaxf(v0.w, 0.f));
    }
    if (t < 512) s += ws[t];                  // dir1 per-block partial sums

    for (int o = 32; o; o >>= 1) s += __shfl_down(s, o, 64);
    const int lane = t & 63, wave = t >> 6;
    if (lane == 0) s_wsum[wave] = s;
    __syncthreads();
    if (t == 0) {
        float tot = 0.f;
#pragma unroll
        for (int w = 0; w < 16; ++w) tot += s_wsum[w];
        out[0] = tot * 1e-4f;
    }
}

extern "C" void kernel_launch(void* const* d_in, const int* in_sizes, int n_in,
                              void* d_out, int out_size, void* d_ws, size_t ws_size,
                              hipStream_t stream) {
    const float* shape = (const float*)d_in[0];   // (8, 8192, 6) — use first 3
    const float* skel  = (const float*)d_in[1];   // (8, 2048, 3)
    float* out         = (float*)d_out;           // scalar
    float* ws          = (float*)d_ws;            // 66048 floats = 258 KB

    cd_main<<<1024, 256, 0, stream>>>(shape, skel, ws);
    cd_reduce<<<1, 1024, 0, stream>>>(ws, out);
}